// Round 1
// baseline (840.080 us; speedup 1.0000x reference)
//
#include <hip/hip_runtime.h>
#include <stdint.h>

// Problem constants (from reference): B=4, Sq=Skv=1024, H=16, D=64, DM=1024, MRP=32
static constexpr int B_ = 4, S_ = 1024, H_ = 16, D_ = 64, DM_ = 1024;
// sqrt(64) * 1024^0.25 computed in fp32 exactly as jnp/np would:
// powf(1024,.25) -> 5.656854152679443 (0x40B504F3), *8 exact.
static constexpr float SF_ = 45.254833221435546875f;

__device__ __forceinline__ int dot4(int a, int b, int c) {
#if __has_builtin(__builtin_amdgcn_sdot4)
  return __builtin_amdgcn_sdot4(a, b, c, false);
#else
  c += ((a << 24) >> 24) * ((b << 24) >> 24);
  c += ((a << 16) >> 24) * ((b << 16) >> 24);
  c += ((a <<  8) >> 24) * ((b <<  8) >> 24);
  c += ( a        >> 24) * ( b        >> 24);
  return c;
#endif
}

// scale = absmax/127 + 1e-8, same op order as reference act_quant
__device__ __forceinline__ float slot_scale(const unsigned* s) {
  return __uint_as_float(*s) / 127.0f + 1e-8f;
}

__device__ __forceinline__ float quantf(float x, float s) {
  // reference: clip(round(x/scale), -127, 127); rintf = round-half-even like jnp.round
  return fminf(fmaxf(rintf(x / s), -127.f), 127.f);
}

__global__ void zero_slots_kernel(unsigned* slots) {
  if (threadIdx.x < 16) slots[threadIdx.x] = 0u;
}

__global__ __launch_bounds__(256) void absmax_kernel(const float* __restrict__ x, int n4,
                                                     unsigned* __restrict__ slot) {
  int i = blockIdx.x * 256 + threadIdx.x;
  const int stride = gridDim.x * 256;
  float m = 0.f;
  const float4* x4 = (const float4*)x;
  for (; i < n4; i += stride) {
    float4 v = x4[i];
    m = fmaxf(m, fmaxf(fmaxf(fabsf(v.x), fabsf(v.y)), fmaxf(fabsf(v.z), fabsf(v.w))));
  }
#pragma unroll
  for (int off = 32; off; off >>= 1) m = fmaxf(m, __shfl_xor(m, off));
  if ((threadIdx.x & 63) == 0) atomicMax(slot, __float_as_uint(m));
}

__global__ __launch_bounds__(256) void quantize_kernel(const float* __restrict__ x, int n4,
                                                       const unsigned* __restrict__ slot,
                                                       int8_t* __restrict__ out) {
  const float s = slot_scale(slot);
  int i = blockIdx.x * 256 + threadIdx.x;
  const int stride = gridDim.x * 256;
  const float4* x4 = (const float4*)x;
  for (; i < n4; i += stride) {
    float4 v = x4[i];
    char4 q;
    q.x = (signed char)(int)quantf(v.x, s);
    q.y = (signed char)(int)quantf(v.y, s);
    q.z = (signed char)(int)quantf(v.z, s);
    q.w = (signed char)(int)quantf(v.w, s);
    *(char4*)&out[4 * (size_t)i] = q;
  }
}

// Quantize weight [K=1024, N=1024] and write transposed int8 [N][K]
__global__ __launch_bounds__(256) void quantW_kernel(const float* __restrict__ w,
                                                     const unsigned* __restrict__ slot,
                                                     int8_t* __restrict__ wt) {
  __shared__ int8_t t[64][80];  // [n][k], row stride 80 (16B aligned, conflict-poor)
  const float s = slot_scale(slot);
  const int k0 = blockIdx.y * 64, n0 = blockIdx.x * 64;
  const int tid = threadIdx.x;
#pragma unroll
  for (int rr = 0; rr < 4; rr++) {
    const int row = (tid >> 4) + rr * 16;   // k within tile
    const int col = (tid & 15) * 4;         // n within tile
    float4 v = *(const float4*)&w[(size_t)(k0 + row) * DM_ + n0 + col];
    t[col + 0][row] = (signed char)(int)quantf(v.x, s);
    t[col + 1][row] = (signed char)(int)quantf(v.y, s);
    t[col + 2][row] = (signed char)(int)quantf(v.z, s);
    t[col + 3][row] = (signed char)(int)quantf(v.w, s);
  }
  __syncthreads();
  const int nr = tid >> 2, kc = (tid & 3) * 16;
  *(int4*)&wt[(size_t)(n0 + nr) * DM_ + k0 + kc] = *(const int4*)&t[nr][kc];
}

// C[M,N] = (float)(A8[M,K] . Bt8[N,K]^T) * (sA*sB) + bias[N]; optional fused absmax of C.
__global__ __launch_bounds__(256) void gemm_i8_kernel(
    const int8_t* __restrict__ A, const int8_t* __restrict__ Bt,
    const unsigned* __restrict__ slotA, const unsigned* __restrict__ slotB,
    const float* __restrict__ bias, float* __restrict__ C,
    int M, int N, int K, unsigned* __restrict__ amax_out) {
  __shared__ int8_t As[64][80];
  __shared__ int8_t Bs[64][80];
  const int m0 = blockIdx.y * 64, n0 = blockIdx.x * 64;
  const int tid = threadIdx.x;
  const int lr = tid >> 2, lc = (tid & 3) * 16;  // staging: 16B per thread per tile
  const int ty = tid >> 4, tx = tid & 15;        // compute: 4x4 outputs, rows ty+16i, cols tx+16j
  int acc[4][4] = {};
  for (int kc = 0; kc < K; kc += 64) {
    __syncthreads();
    *(int4*)&As[lr][lc] = *(const int4*)&A[(size_t)(m0 + lr) * K + kc + lc];
    *(int4*)&Bs[lr][lc] = *(const int4*)&Bt[(size_t)(n0 + lr) * K + kc + lc];
    __syncthreads();
#pragma unroll
    for (int kq = 0; kq < 4; kq++) {
      int4 a4[4], b4[4];
#pragma unroll
      for (int i = 0; i < 4; i++) a4[i] = *(const int4*)&As[ty + 16 * i][kq * 16];
#pragma unroll
      for (int j = 0; j < 4; j++) b4[j] = *(const int4*)&Bs[tx + 16 * j][kq * 16];
#pragma unroll
      for (int i = 0; i < 4; i++)
#pragma unroll
        for (int j = 0; j < 4; j++) {
          acc[i][j] = dot4(a4[i].x, b4[j].x, acc[i][j]);
          acc[i][j] = dot4(a4[i].y, b4[j].y, acc[i][j]);
          acc[i][j] = dot4(a4[i].z, b4[j].z, acc[i][j]);
          acc[i][j] = dot4(a4[i].w, b4[j].w, acc[i][j]);
        }
    }
  }
  const float sAB = slot_scale(slotA) * slot_scale(slotB);
  float am = 0.f;
#pragma unroll
  for (int i = 0; i < 4; i++)
#pragma unroll
    for (int j = 0; j < 4; j++) {
      const int m = m0 + ty + 16 * i, n = n0 + tx + 16 * j;
      const float c = (float)acc[i][j] * sAB + bias[n];
      C[(size_t)m * N + n] = c;
      am = fmaxf(am, fabsf(c));
    }
  if (amax_out) {
#pragma unroll
    for (int off = 32; off; off >>= 1) am = fmaxf(am, __shfl_xor(am, off));
    if ((tid & 63) == 0) atomicMax(amax_out, __float_as_uint(am));
  }
}

__device__ __forceinline__ float score_at(const int* qreg, const int8_t (*ks)[80], int kcol,
                                          int i_glob, int j_glob, float sqk,
                                          const float* biasT) {
  const int4* kp = (const int4*)&ks[kcol][0];
  int4 k0 = kp[0], k1 = kp[1], k2 = kp[2], k3 = kp[3];
  int kr[16] = {k0.x, k0.y, k0.z, k0.w, k1.x, k1.y, k1.z, k1.w,
                k2.x, k2.y, k2.z, k2.w, k3.x, k3.y, k3.z, k3.w};
  int acc = 0;
#pragma unroll
  for (int kk = 0; kk < 16; kk++) acc = dot4(qreg[kk], kr[kk], acc);
  int dp = i_glob - j_glob + 32;
  dp = dp < 0 ? 0 : (dp > 64 ? 64 : dp);
  // reference: ((matmul*(sq*sk)) + bias) / scale_factor
  return ((float)acc * sqk + biasT[dp]) / SF_;
}

// Fused attention: one block = (b, h, 64 q rows). Two passes over kv tiles:
// pass1 exact row max (matches reference's global-max softmax), pass2 exp/sum/PV.
__global__ __launch_bounds__(256) void attn_kernel(
    const int8_t* __restrict__ q8, const int8_t* __restrict__ k8,
    const int8_t* __restrict__ v8, const unsigned* __restrict__ slots,
    const float* __restrict__ rel, float* __restrict__ ao,
    unsigned* __restrict__ amax_out) {
  __shared__ int8_t ks[64][80];
  __shared__ float vs[64][68];
  __shared__ float ps[64][68];
  __shared__ float biasT[72];
  const int qt = blockIdx.x, h = blockIdx.y, b = blockIdx.z;
  const int tid = threadIdx.x;
  const int r = tid >> 2, qd = tid & 3;  // 4 threads per q-row
  const float sqk = slot_scale(slots + 6) * slot_scale(slots + 7);
  const float sv = slot_scale(slots + 8);
  if (tid < 65) biasT[tid] = rel[tid * D_ + h];  // rel_pos_emb[pos, h]

  // own q row -> registers (int8 [B,S,H,D] layout, 64B contiguous)
  int qreg[16];
  {
    const int4* qp = (const int4*)&q8[(((size_t)b * S_ + qt * 64 + r) * H_ + h) * D_];
    int4 t0 = qp[0], t1 = qp[1], t2 = qp[2], t3 = qp[3];
    qreg[0] = t0.x; qreg[1] = t0.y; qreg[2] = t0.z; qreg[3] = t0.w;
    qreg[4] = t1.x; qreg[5] = t1.y; qreg[6] = t1.z; qreg[7] = t1.w;
    qreg[8] = t2.x; qreg[9] = t2.y; qreg[10] = t2.z; qreg[11] = t2.w;
    qreg[12] = t3.x; qreg[13] = t3.y; qreg[14] = t3.z; qreg[15] = t3.w;
  }
  const int i_glob = qt * 64 + r;

  // ---- pass 1: exact row max ----
  float mloc = -3.4e38f;
  for (int t = 0; t < 16; t++) {
    __syncthreads();
    *(int4*)&ks[r][qd * 16] =
        *(const int4*)&k8[(((size_t)b * S_ + t * 64 + r) * H_ + h) * D_ + qd * 16];
    __syncthreads();
#pragma unroll 4
    for (int cc = 0; cc < 16; cc++) {
      const int kcol = qd + cc * 4;
      mloc = fmaxf(mloc, score_at(qreg, ks, kcol, i_glob, t * 64 + kcol, sqk, biasT));
    }
  }
  mloc = fmaxf(mloc, __shfl_xor(mloc, 1));
  mloc = fmaxf(mloc, __shfl_xor(mloc, 2));
  const float M = mloc;

  // ---- pass 2: exp, sum, P.V ----
  float o[16];
#pragma unroll
  for (int d = 0; d < 16; d++) o[d] = 0.f;
  float lsum = 0.f;
  for (int t = 0; t < 16; t++) {
    __syncthreads();
    *(int4*)&ks[r][qd * 16] =
        *(const int4*)&k8[(((size_t)b * S_ + t * 64 + r) * H_ + h) * D_ + qd * 16];
    {
      int4 vv = *(const int4*)&v8[(((size_t)b * S_ + t * 64 + r) * H_ + h) * D_ + qd * 16];
      const signed char* vb = (const signed char*)&vv;
#pragma unroll
      for (int c2 = 0; c2 < 16; c2++) vs[r][qd * 16 + c2] = (float)vb[c2];
    }
    __syncthreads();
#pragma unroll 4
    for (int cc = 0; cc < 16; cc++) {
      const int kcol = qd + cc * 4;
      const float sc = score_at(qreg, ks, kcol, i_glob, t * 64 + kcol, sqk, biasT);
      const float e = expf(sc - M);
      lsum += e;
      ps[r][kcol] = e;
    }
    __syncthreads();
#pragma unroll 8
    for (int kk = 0; kk < 64; kk++) {
      const float p = ps[r][kk];
      const float4* vrow = (const float4*)&vs[kk][qd * 16];
      float4 v0 = vrow[0], v1 = vrow[1], v2 = vrow[2], v3 = vrow[3];
      float vvv[16] = {v0.x, v0.y, v0.z, v0.w, v1.x, v1.y, v1.z, v1.w,
                       v2.x, v2.y, v2.z, v2.w, v3.x, v3.y, v3.z, v3.w};
#pragma unroll
      for (int d = 0; d < 16; d++) o[d] += p * vvv[d];
    }
  }
  lsum += __shfl_xor(lsum, 1);
  lsum += __shfl_xor(lsum, 2);
  const float L = lsum + 1e-6f;  // reference: / (sum + 1e-6)

  float am = 0.f;
  float* orow = &ao[((size_t)b * S_ + i_glob) * DM_ + h * D_ + qd * 16];
#pragma unroll
  for (int d = 0; d < 16; d++) {
    const float val = (o[d] / L) * sv;  // * sv per reference (weights unquantized)
    orow[d] = val;
    am = fmaxf(am, fabsf(val));
  }
#pragma unroll
  for (int off = 32; off; off >>= 1) am = fmaxf(am, __shfl_xor(am, off));
  if ((tid & 63) == 0) atomicMax(amax_out, __float_as_uint(am));
}

extern "C" void kernel_launch(void* const* d_in, const int* in_sizes, int n_in,
                              void* d_out, int out_size, void* d_ws, size_t ws_size,
                              hipStream_t stream) {
  const float* inputs_q  = (const float*)d_in[0];
  const float* inputs_kv = (const float*)d_in[1];
  const float* Wq = (const float*)d_in[2];
  const float* bq = (const float*)d_in[3];
  const float* Wk = (const float*)d_in[4];
  const float* bk = (const float*)d_in[5];
  const float* Wv = (const float*)d_in[6];
  const float* bv = (const float*)d_in[7];
  const float* Wo = (const float*)d_in[8];
  const float* bo = (const float*)d_in[9];
  const float* rel = (const float*)d_in[10];
  float* out = (float*)d_out;

  char* ws = (char*)d_ws;
  constexpr size_t MB = 1024 * 1024;
  // slot map: 0 sx_q, 1 sx_kv, 2 sWq, 3 sWk, 4 sWv, 5 sWo, 6 sq, 7 sk, 8 sv, 9 sao
  unsigned* slots = (unsigned*)ws;              // 256 B
  int8_t* xq8  = (int8_t*)(ws + 256);           // 4 MB
  int8_t* xkv8 = xq8 + 4 * MB;                  // 4 MB
  int8_t* wq8  = xkv8 + 4 * MB;                 // 1 MB (transposed [N][K])
  int8_t* wk8  = wq8 + MB;
  int8_t* wv8  = wk8 + MB;
  int8_t* wo8  = wv8 + MB;
  int8_t* q8   = wo8 + MB;                      // 4 MB each, [B,S,H,D]
  int8_t* k8   = q8 + 4 * MB;
  int8_t* v8   = k8 + 4 * MB;
  int8_t* ao8  = v8 + 4 * MB;                   // 4 MB
  float* qf = (float*)(ao8 + 4 * MB);           // 16 MB each
  float* kf = qf + 4 * MB;
  float* vf = kf + 4 * MB;
  float* aof = qf;                              // reuse (qf dead after q8 made)
  (void)ws_size; (void)in_sizes; (void)n_in; (void)out_size;

  const int n4_x = (B_ * S_ * DM_) / 4;   // 1048576
  const int n4_w = (DM_ * DM_) / 4;       // 262144

  zero_slots_kernel<<<1, 64, 0, stream>>>(slots);

  absmax_kernel<<<1024, 256, 0, stream>>>(inputs_q,  n4_x, slots + 0);
  absmax_kernel<<<1024, 256, 0, stream>>>(inputs_kv, n4_x, slots + 1);
  absmax_kernel<<<512, 256, 0, stream>>>(Wq, n4_w, slots + 2);
  absmax_kernel<<<512, 256, 0, stream>>>(Wk, n4_w, slots + 3);
  absmax_kernel<<<512, 256, 0, stream>>>(Wv, n4_w, slots + 4);
  absmax_kernel<<<512, 256, 0, stream>>>(Wo, n4_w, slots + 5);

  quantize_kernel<<<1024, 256, 0, stream>>>(inputs_q,  n4_x, slots + 0, xq8);
  quantize_kernel<<<1024, 256, 0, stream>>>(inputs_kv, n4_x, slots + 1, xkv8);
  quantW_kernel<<<dim3(16, 16), 256, 0, stream>>>(Wq, slots + 2, wq8);
  quantW_kernel<<<dim3(16, 16), 256, 0, stream>>>(Wk, slots + 3, wk8);
  quantW_kernel<<<dim3(16, 16), 256, 0, stream>>>(Wv, slots + 4, wv8);
  quantW_kernel<<<dim3(16, 16), 256, 0, stream>>>(Wo, slots + 5, wo8);

  // projections: [4096,1024] x [1024,1024]^T ; fused absmax of q/k/v
  gemm_i8_kernel<<<dim3(16, 64), 256, 0, stream>>>(xq8,  wq8, slots + 0, slots + 2, bq, qf,
                                                   B_ * S_, DM_, DM_, slots + 6);
  gemm_i8_kernel<<<dim3(16, 64), 256, 0, stream>>>(xkv8, wk8, slots + 1, slots + 3, bk, kf,
                                                   B_ * S_, DM_, DM_, slots + 7);
  gemm_i8_kernel<<<dim3(16, 64), 256, 0, stream>>>(xkv8, wv8, slots + 1, slots + 4, bv, vf,
                                                   B_ * S_, DM_, DM_, slots + 8);

  quantize_kernel<<<1024, 256, 0, stream>>>(qf, n4_x, slots + 6, q8);
  quantize_kernel<<<1024, 256, 0, stream>>>(kf, n4_x, slots + 7, k8);
  quantize_kernel<<<1024, 256, 0, stream>>>(vf, n4_x, slots + 8, v8);

  attn_kernel<<<dim3(16, 16, 4), 256, 0, stream>>>(q8, k8, v8, slots, rel, aof, slots + 9);

  quantize_kernel<<<1024, 256, 0, stream>>>(aof, n4_x, slots + 9, ao8);

  gemm_i8_kernel<<<dim3(16, 64), 256, 0, stream>>>(ao8, wo8, slots + 9, slots + 5, bo, out,
                                                   B_ * S_, DM_, DM_, nullptr);
}

// Round 2
// 646.402 us; speedup vs baseline: 1.2996x; 1.2996x over previous
//
#include <hip/hip_runtime.h>
#include <stdint.h>

// B=4, Sq=Skv=1024, H=16, D=64, DM=1024, MRP=32
static constexpr int B_ = 4, S_ = 1024, H_ = 16, D_ = 64, DM_ = 1024;
// sqrt(64) * 1024^0.25 in fp32 exactly as np computes it
static constexpr float SF_ = 45.254833221435546875f;
static constexpr float RCP_SF_ = 1.0f / SF_;  // compile-time, correctly rounded

typedef unsigned short u16;
typedef __attribute__((ext_vector_type(8))) short bf16x8;
typedef __attribute__((ext_vector_type(4))) float f32x4;

#define MFMA_BF16 __builtin_amdgcn_mfma_f32_16x16x32_bf16

__device__ __forceinline__ float slot_scale(const unsigned* s) {
  return __uint_as_float(*s) / 127.0f + 1e-8f;  // absmax/127 + 1e-8, reference order
}
__device__ __forceinline__ float quantf(float x, float s) {
  // reference: clip(round(x/scale), -127, 127); rintf = RNE like jnp.round
  return fminf(fmaxf(rintf(x / s), -127.f), 127.f);
}
__device__ __forceinline__ u16 qb16(float x, float s) {
  // quantized value is a small integer -> bf16 truncation is exact
  return (u16)(__float_as_uint(quantf(x, s)) >> 16);
}
__device__ __forceinline__ u16 b16rne(float x) {  // float -> bf16 RNE
  unsigned u = __float_as_uint(x);
  return (u16)((u + 0x7FFFu + ((u >> 16) & 1u)) >> 16);
}
__device__ __forceinline__ float b16f(u16 h) { return __uint_as_float(((unsigned)h) << 16); }
__device__ __forceinline__ float div_sf(float t2) {
  // correctly-rounded t2/SF_ via Markstein fma sequence (3 VALU ops)
  float q0 = t2 * RCP_SF_;
  float r = fmaf(-SF_, q0, t2);
  return fmaf(r, RCP_SF_, q0);
}

__global__ void zero_slots_kernel(unsigned* slots) {
  if (threadIdx.x < 16) slots[threadIdx.x] = 0u;
}

__global__ __launch_bounds__(256) void absmax_kernel(const float* __restrict__ x, int n4,
                                                     unsigned* __restrict__ slot) {
  int i = blockIdx.x * 256 + threadIdx.x;
  const int stride = gridDim.x * 256;
  float m = 0.f;
  const float4* x4 = (const float4*)x;
  for (; i < n4; i += stride) {
    float4 v = x4[i];
    m = fmaxf(m, fmaxf(fmaxf(fabsf(v.x), fabsf(v.y)), fmaxf(fabsf(v.z), fabsf(v.w))));
  }
#pragma unroll
  for (int off = 32; off; off >>= 1) m = fmaxf(m, __shfl_xor(m, off));
  if ((threadIdx.x & 63) == 0) atomicMax(slot, __float_as_uint(m));
}

// float -> quantized bf16 values (8 elems/thread)
__global__ __launch_bounds__(256) void quantize_bf16_kernel(const float* __restrict__ x, int n8,
                                                            const unsigned* __restrict__ slot,
                                                            u16* __restrict__ out) {
  const float s = slot_scale(slot);
  int i = blockIdx.x * 256 + threadIdx.x;
  const int stride = gridDim.x * 256;
  for (; i < n8; i += stride) {
    float4 v0 = *((const float4*)x + 2 * (size_t)i);
    float4 v1 = *((const float4*)x + 2 * (size_t)i + 1);
    int4 o;
    o.x = (int)qb16(v0.x, s) | ((int)qb16(v0.y, s) << 16);
    o.y = (int)qb16(v0.z, s) | ((int)qb16(v0.w, s) << 16);
    o.z = (int)qb16(v1.x, s) | ((int)qb16(v1.y, s) << 16);
    o.w = (int)qb16(v1.z, s) | ((int)qb16(v1.w, s) << 16);
    *((int4*)out + i) = o;
  }
}

// Quantize weight [K,N] -> transposed bf16 [N][K]
__global__ __launch_bounds__(256) void quantW_kernel(const float* __restrict__ w,
                                                     const unsigned* __restrict__ slot,
                                                     u16* __restrict__ wt) {
  __shared__ u16 t[64][72];
  const float s = slot_scale(slot);
  const int k0 = blockIdx.y * 64, n0 = blockIdx.x * 64;
  const int tid = threadIdx.x;
#pragma unroll
  for (int rr = 0; rr < 4; rr++) {
    const int row = (tid >> 4) + rr * 16;  // k
    const int col = (tid & 15) * 4;        // n
    float4 v = *(const float4*)&w[(size_t)(k0 + row) * DM_ + n0 + col];
    t[col + 0][row] = qb16(v.x, s);
    t[col + 1][row] = qb16(v.y, s);
    t[col + 2][row] = qb16(v.z, s);
    t[col + 3][row] = qb16(v.w, s);
  }
  __syncthreads();
  const int nr = tid >> 2, kc = (tid & 3) * 16;
  *(int4*)&wt[(size_t)(n0 + nr) * DM_ + k0 + kc] = *(const int4*)&t[nr][kc];
  *(int4*)&wt[(size_t)(n0 + nr) * DM_ + k0 + kc + 8] = *(const int4*)&t[nr][kc + 8];
}

// C[M,N] = exact-int (A . Bt^T) * (sA*sB) + bias; A,Bt hold int-valued bf16.
// 64x64 tile, 4 waves in 2x2 quadrants, mfma_f32_16x16x32_bf16.
__global__ __launch_bounds__(256) void gemm_bf16q_kernel(
    const u16* __restrict__ A, const u16* __restrict__ Bt,
    const unsigned* __restrict__ slotA, const unsigned* __restrict__ slotB,
    const float* __restrict__ bias, float* __restrict__ C,
    int M, int N, int K, unsigned* __restrict__ amax_out) {
  __shared__ u16 As[64][72];
  __shared__ u16 Bs[64][72];
  const int m0 = blockIdx.y * 64, n0 = blockIdx.x * 64;
  const int tid = threadIdx.x;
  const int w = tid >> 6, lane = tid & 63, c = lane & 15, g = lane >> 4;
  const int wr = w >> 1, wc = w & 1;
  const int sr = tid >> 2, seg = tid & 3;
  f32x4 acc[2][2] = {};
  for (int kc = 0; kc < K; kc += 64) {
    __syncthreads();
    { const u16* a = &A[(size_t)(m0 + sr) * K + kc + seg * 16];
      *(int4*)&As[sr][seg * 16] = *(const int4*)a;
      *(int4*)&As[sr][seg * 16 + 8] = *(const int4*)(a + 8);
      const u16* bsrc = &Bt[(size_t)(n0 + sr) * K + kc + seg * 16];
      *(int4*)&Bs[sr][seg * 16] = *(const int4*)bsrc;
      *(int4*)&Bs[sr][seg * 16 + 8] = *(const int4*)(bsrc + 8); }
    __syncthreads();
#pragma unroll
    for (int ks = 0; ks < 2; ks++) {
      bf16x8 a0 = *(const bf16x8*)&As[wr * 32 + c][ks * 32 + g * 8];
      bf16x8 a1 = *(const bf16x8*)&As[wr * 32 + 16 + c][ks * 32 + g * 8];
      bf16x8 b0 = *(const bf16x8*)&Bs[wc * 32 + c][ks * 32 + g * 8];
      bf16x8 b1 = *(const bf16x8*)&Bs[wc * 32 + 16 + c][ks * 32 + g * 8];
      acc[0][0] = MFMA_BF16(a0, b0, acc[0][0], 0, 0, 0);
      acc[0][1] = MFMA_BF16(a0, b1, acc[0][1], 0, 0, 0);
      acc[1][0] = MFMA_BF16(a1, b0, acc[1][0], 0, 0, 0);
      acc[1][1] = MFMA_BF16(a1, b1, acc[1][1], 0, 0, 0);
    }
  }
  const float sAB = slot_scale(slotA) * slot_scale(slotB);
  float am = 0.f;
#pragma unroll
  for (int ti = 0; ti < 2; ti++)
#pragma unroll
    for (int tj = 0; tj < 2; tj++)
#pragma unroll
      for (int reg = 0; reg < 4; reg++) {
        const int m = m0 + wr * 32 + ti * 16 + 4 * g + reg;
        const int n = n0 + wc * 32 + tj * 16 + c;
        const float val = __fadd_rn(__fmul_rn(acc[ti][tj][reg], sAB), bias[n]);
        C[(size_t)m * N + n] = val;
        am = fmaxf(am, fabsf(val));
      }
  if (amax_out) {
#pragma unroll
    for (int off = 32; off; off >>= 1) am = fmaxf(am, __shfl_xor(am, off));
    if (lane == 0) atomicMax(amax_out, __float_as_uint(am));
  }
}

// Fused attention: block = (qt 64 rows, h, b); 4 waves x 16 q-rows.
// Two exact passes; scores via bf16 MFMA (exact int), PV via 3-way bf16 split MFMA.
__global__ __launch_bounds__(256) void attn_kernel(
    const u16* __restrict__ qb_, const u16* __restrict__ kb_, const u16* __restrict__ vb_,
    const unsigned* __restrict__ slots, const float* __restrict__ rel,
    float* __restrict__ ao, unsigned* __restrict__ amax_out) {
  __shared__ u16 kbf[64][72];
  __shared__ u16 vT[64][72];          // V^T [d][kv], kv XOR-swizzled by (d>>3)
  __shared__ u16 Pc[3][4][16][72];    // [comp][wave][q][kv^((q>>2)<<3)]
  __shared__ float biasT[68];
  const int qt = blockIdx.x, h = blockIdx.y, b = blockIdx.z;
  const int tid = threadIdx.x;
  const int w = tid >> 6, lane = tid & 63;
  const int c = lane & 15, g = lane >> 4;
  const float sqk = slot_scale(slots + 6) * slot_scale(slots + 7);
  const float sv = slot_scale(slots + 8);
  if (tid < 65) biasT[tid] = rel[tid * D_ + h];
  const int qbase = qt * 64 + w * 16;
  const size_t qrow = ((size_t)(b * S_) + qbase + c) * DM_ + h * 64;
  const bf16x8 qA0 = *(const bf16x8*)&qb_[qrow + g * 8];
  const bf16x8 qA1 = *(const bf16x8*)&qb_[qrow + 32 + g * 8];
  const int sr = tid >> 2, sseg = tid & 3;  // K staging map
  const int r2 = tid >> 3, dq = tid & 7;    // V staging map
  const int qg0 = qbase + 4 * g;

  // ---- pass 1: exact row max ----
  float mrow[4] = {-3.4e38f, -3.4e38f, -3.4e38f, -3.4e38f};
  for (int ch = 0; ch < 16; ch++) {
    __syncthreads();
    { const u16* src = &kb_[((size_t)(b * S_) + ch * 64 + sr) * DM_ + h * 64 + sseg * 16];
      *(int4*)&kbf[sr][sseg * 16] = *(const int4*)src;
      *(int4*)&kbf[sr][sseg * 16 + 8] = *(const int4*)(src + 8); }
    __syncthreads();
#pragma unroll
    for (int t = 0; t < 4; t++) {
      f32x4 sacc = {0.f, 0.f, 0.f, 0.f};
      bf16x8 k0 = *(const bf16x8*)&kbf[t * 16 + c][g * 8];
      bf16x8 k1 = *(const bf16x8*)&kbf[t * 16 + c][32 + g * 8];
      sacc = MFMA_BF16(qA0, k0, sacc, 0, 0, 0);
      sacc = MFMA_BF16(qA1, k1, sacc, 0, 0, 0);
      const int jg = ch * 64 + t * 16 + c;
#pragma unroll
      for (int reg = 0; reg < 4; reg++) {
        int dp = qg0 + reg - jg + 32;
        dp = dp < 0 ? 0 : (dp > 64 ? 64 : dp);
        const float t2 = __fadd_rn(__fmul_rn(sacc[reg], sqk), biasT[dp]);
        mrow[reg] = fmaxf(mrow[reg], div_sf(t2));
      }
    }
  }
#pragma unroll
  for (int off = 1; off <= 8; off <<= 1)
#pragma unroll
    for (int reg = 0; reg < 4; reg++) mrow[reg] = fmaxf(mrow[reg], __shfl_xor(mrow[reg], off));

  // ---- pass 2: exp, 3-way bf16 split, PV MFMA ----
  f32x4 oacc[4] = {};
  float ls[4] = {0.f, 0.f, 0.f, 0.f};
  for (int ch = 0; ch < 16; ch++) {
    __syncthreads();
    { const u16* src = &kb_[((size_t)(b * S_) + ch * 64 + sr) * DM_ + h * 64 + sseg * 16];
      *(int4*)&kbf[sr][sseg * 16] = *(const int4*)src;
      *(int4*)&kbf[sr][sseg * 16 + 8] = *(const int4*)(src + 8); }
    { const u16* s0 = &vb_[((size_t)(b * S_) + ch * 64 + 2 * r2) * DM_ + h * 64 + dq * 8];
      int4 va = *(const int4*)s0;
      int4 vbk = *(const int4*)(s0 + DM_);
      const u16* pa = (const u16*)&va;
      const u16* pb = (const u16*)&vbk;
      const int kvp = (2 * r2) ^ (dq << 3);
#pragma unroll
      for (int i = 0; i < 8; i++) {
        unsigned pair = (unsigned)pa[i] | ((unsigned)pb[i] << 16);
        *(unsigned*)&vT[dq * 8 + i][kvp] = pair;
      }
    }
    __syncthreads();
#pragma unroll
    for (int t = 0; t < 4; t++) {
      f32x4 sacc = {0.f, 0.f, 0.f, 0.f};
      bf16x8 k0 = *(const bf16x8*)&kbf[t * 16 + c][g * 8];
      bf16x8 k1 = *(const bf16x8*)&kbf[t * 16 + c][32 + g * 8];
      sacc = MFMA_BF16(qA0, k0, sacc, 0, 0, 0);
      sacc = MFMA_BF16(qA1, k1, sacc, 0, 0, 0);
      const int jg = ch * 64 + t * 16 + c;
      const int kv = t * 16 + c;
      const int kvw = kv ^ (g << 3);
#pragma unroll
      for (int reg = 0; reg < 4; reg++) {
        int dp = qg0 + reg - jg + 32;
        dp = dp < 0 ? 0 : (dp > 64 ? 64 : dp);
        const float t2 = __fadd_rn(__fmul_rn(sacc[reg], sqk), biasT[dp]);
        const float sc = div_sf(t2);
        const float e = expf(sc - mrow[reg]);
        ls[reg] += e;
        const u16 hu = b16rne(e);
        const float rr1 = e - b16f(hu);
        const u16 mu = b16rne(rr1);
        const float rr2 = rr1 - b16f(mu);
        const u16 lu = b16rne(rr2);
        const int ql = 4 * g + reg;
        Pc[0][w][ql][kvw] = hu;
        Pc[1][w][ql][kvw] = mu;
        Pc[2][w][ql][kvw] = lu;
      }
    }
#pragma unroll
    for (int ks = 0; ks < 2; ks++) {
      bf16x8 vb4[4];
#pragma unroll
      for (int n = 0; n < 4; n++) {
        const int d = 16 * n + c;
        const int kvv = (ks * 32 + g * 8) ^ (((d >> 3) & 7) << 3);
        vb4[n] = *(const bf16x8*)&vT[d][kvv];
      }
      const int kvp2 = (ks * 32 + g * 8) ^ ((c >> 2) << 3);
#pragma unroll
      for (int comp = 0; comp < 3; comp++) {
        bf16x8 pa = *(const bf16x8*)&Pc[comp][w][c][kvp2];
#pragma unroll
        for (int n = 0; n < 4; n++) oacc[n] = MFMA_BF16(pa, vb4[n], oacc[n], 0, 0, 0);
      }
    }
  }
#pragma unroll
  for (int off = 1; off <= 8; off <<= 1)
#pragma unroll
    for (int reg = 0; reg < 4; reg++) ls[reg] += __shfl_xor(ls[reg], off);
  float am = 0.f;
#pragma unroll
  for (int reg = 0; reg < 4; reg++) {
    const float L = ls[reg] + 1e-6f;  // reference: /(sum + 1e-6)
    const size_t orow = ((size_t)(b * S_) + qbase + 4 * g + reg) * DM_ + h * 64;
#pragma unroll
    for (int n = 0; n < 4; n++) {
      const float val = __fmul_rn(oacc[n][reg] / L, sv);
      ao[orow + n * 16 + c] = val;
      am = fmaxf(am, fabsf(val));
    }
  }
#pragma unroll
  for (int off = 1; off <= 32; off <<= 1) am = fmaxf(am, __shfl_xor(am, off));
  if (lane == 0) atomicMax(amax_out, __float_as_uint(am));
}

extern "C" void kernel_launch(void* const* d_in, const int* in_sizes, int n_in,
                              void* d_out, int out_size, void* d_ws, size_t ws_size,
                              hipStream_t stream) {
  const float* inputs_q  = (const float*)d_in[0];
  const float* inputs_kv = (const float*)d_in[1];
  const float* Wq = (const float*)d_in[2];
  const float* bq = (const float*)d_in[3];
  const float* Wk = (const float*)d_in[4];
  const float* bk = (const float*)d_in[5];
  const float* Wv = (const float*)d_in[6];
  const float* bv = (const float*)d_in[7];
  const float* Wo = (const float*)d_in[8];
  const float* bo = (const float*)d_in[9];
  const float* rel = (const float*)d_in[10];
  float* out = (float*)d_out;

  char* ws = (char*)d_ws;
  constexpr size_t MB = 1024 * 1024;
  // slots: 0 sx_q, 1 sx_kv, 2 sWq, 3 sWk, 4 sWv, 5 sWo, 6 sq, 7 sk, 8 sv, 9 sao
  unsigned* slots = (unsigned*)ws;
  u16* xq_b  = (u16*)(ws + 1024);            // 8 MB [4096][1024]
  u16* xkv_b = (u16*)((char*)xq_b + 8 * MB); // 8 MB
  u16* wq_b  = (u16*)((char*)xkv_b + 8 * MB);// 2 MB each, [N][K]
  u16* wk_b  = (u16*)((char*)wq_b + 2 * MB);
  u16* wv_b  = (u16*)((char*)wk_b + 2 * MB);
  u16* wo_b  = (u16*)((char*)wv_b + 2 * MB);
  u16* q_b   = (u16*)((char*)wo_b + 2 * MB); // 8 MB each
  u16* k_b   = (u16*)((char*)q_b + 8 * MB);
  u16* v_b   = (u16*)((char*)k_b + 8 * MB);
  u16* ao_b  = (u16*)((char*)v_b + 8 * MB);
  float* tf  = (float*)((char*)ao_b + 8 * MB); // 16 MB, reused for qf/kf/vf/aof
  (void)ws_size; (void)in_sizes; (void)n_in; (void)out_size;

  const int n4_x = (B_ * S_ * DM_) / 4, n4_w = (DM_ * DM_) / 4;
  const int n8_x = (B_ * S_ * DM_) / 8;

  zero_slots_kernel<<<1, 64, 0, stream>>>(slots);

  absmax_kernel<<<1024, 256, 0, stream>>>(inputs_q,  n4_x, slots + 0);
  absmax_kernel<<<1024, 256, 0, stream>>>(inputs_kv, n4_x, slots + 1);
  absmax_kernel<<<512, 256, 0, stream>>>(Wq, n4_w, slots + 2);
  absmax_kernel<<<512, 256, 0, stream>>>(Wk, n4_w, slots + 3);
  absmax_kernel<<<512, 256, 0, stream>>>(Wv, n4_w, slots + 4);
  absmax_kernel<<<512, 256, 0, stream>>>(Wo, n4_w, slots + 5);

  quantize_bf16_kernel<<<1024, 256, 0, stream>>>(inputs_q,  n8_x, slots + 0, xq_b);
  quantize_bf16_kernel<<<1024, 256, 0, stream>>>(inputs_kv, n8_x, slots + 1, xkv_b);
  quantW_kernel<<<dim3(16, 16), 256, 0, stream>>>(Wq, slots + 2, wq_b);
  quantW_kernel<<<dim3(16, 16), 256, 0, stream>>>(Wk, slots + 3, wk_b);
  quantW_kernel<<<dim3(16, 16), 256, 0, stream>>>(Wv, slots + 4, wv_b);
  quantW_kernel<<<dim3(16, 16), 256, 0, stream>>>(Wo, slots + 5, wo_b);

  gemm_bf16q_kernel<<<dim3(16, 64), 256, 0, stream>>>(xq_b, wq_b, slots + 0, slots + 2,
                                                      bq, tf, B_ * S_, DM_, DM_, slots + 6);
  quantize_bf16_kernel<<<1024, 256, 0, stream>>>(tf, n8_x, slots + 6, q_b);
  gemm_bf16q_kernel<<<dim3(16, 64), 256, 0, stream>>>(xkv_b, wk_b, slots + 1, slots + 3,
                                                      bk, tf, B_ * S_, DM_, DM_, slots + 7);
  quantize_bf16_kernel<<<1024, 256, 0, stream>>>(tf, n8_x, slots + 7, k_b);
  gemm_bf16q_kernel<<<dim3(16, 64), 256, 0, stream>>>(xkv_b, wv_b, slots + 1, slots + 4,
                                                      bv, tf, B_ * S_, DM_, DM_, slots + 8);
  quantize_bf16_kernel<<<1024, 256, 0, stream>>>(tf, n8_x, slots + 8, v_b);

  attn_kernel<<<dim3(16, 16, 4), 256, 0, stream>>>(q_b, k_b, v_b, slots, rel, tf, slots + 9);

  quantize_bf16_kernel<<<1024, 256, 0, stream>>>(tf, n8_x, slots + 9, ao_b);

  gemm_bf16q_kernel<<<dim3(16, 64), 256, 0, stream>>>(ao_b, wo_b, slots + 9, slots + 5,
                                                      bo, out, B_ * S_, DM_, DM_, nullptr);
}

// Round 3
// 396.271 us; speedup vs baseline: 2.1200x; 1.6312x over previous
//
#include <hip/hip_runtime.h>
#include <hip/hip_bf16.h>
#include <stdint.h>

// B=4, Sq=Skv=1024, H=16, D=64, DM=1024, MRP=32
static constexpr int B_ = 4, S_ = 1024, H_ = 16, D_ = 64, DM_ = 1024;
// sqrt(64) * 1024^0.25 in fp32 exactly as np computes it
static constexpr float SF_ = 45.254833221435546875f;
static constexpr float RCP_SF_ = 1.0f / SF_;

typedef unsigned short u16;
typedef __attribute__((ext_vector_type(8))) short bf16x8;
typedef __attribute__((ext_vector_type(4))) float f32x4;

#define MFMA_BF16 __builtin_amdgcn_mfma_f32_16x16x32_bf16

typedef const __attribute__((address_space(1))) void CGV;
typedef __attribute__((address_space(3))) void LDSV;
__device__ __forceinline__ void gload16(const void* g, void* l) {
  __builtin_amdgcn_global_load_lds((CGV*)g, (LDSV*)l, 16, 0, 0);
}

__device__ __forceinline__ float slot_scale(const unsigned* s) {
  return __uint_as_float(*s) / 127.0f + 1e-8f;  // absmax/127 + 1e-8, reference order
}
__device__ __forceinline__ float quantf(float x, float s) {
  return fminf(fmaxf(rintf(x / s), -127.f), 127.f);  // RNE like jnp.round
}
__device__ __forceinline__ u16 f2b(float x) {  // float -> bf16 (HIP conversion)
  union { __hip_bfloat16 h; u16 u; } cv;
  cv.h = __float2bfloat16(x);
  return cv.u;
}
__device__ __forceinline__ float b2f(u16 u) { return __uint_as_float((unsigned)u << 16); }
__device__ __forceinline__ u16 qb16(float x, float s) { return f2b(quantf(x, s)); }
__device__ __forceinline__ float div_sf(float t2) {
  // correctly-rounded t2/SF_ (Markstein)
  float q0 = t2 * RCP_SF_;
  float r = fmaf(-SF_, q0, t2);
  return fmaf(r, RCP_SF_, q0);
}

__global__ void zero_slots_kernel(unsigned* slots) {
  if (threadIdx.x < 16) slots[threadIdx.x] = 0u;
}

struct Ptr6 { const float* p[6]; int n4[6]; };

__global__ __launch_bounds__(256) void absmax6_kernel(Ptr6 a, unsigned* __restrict__ slots) {
  const int y = blockIdx.y;
  const float4* x4 = (const float4*)a.p[y];
  const int n4 = a.n4[y];
  float m = 0.f;
  for (int i = blockIdx.x * 256 + threadIdx.x; i < n4; i += gridDim.x * 256) {
    float4 v = x4[i];
    m = fmaxf(m, fmaxf(fmaxf(fabsf(v.x), fabsf(v.y)), fmaxf(fabsf(v.z), fabsf(v.w))));
  }
#pragma unroll
  for (int off = 32; off; off >>= 1) m = fmaxf(m, __shfl_xor(m, off));
  if ((threadIdx.x & 63) == 0) atomicMax(slots + y, __float_as_uint(m));
}

__device__ __forceinline__ void quant_body(const float* __restrict__ x, int n8, float s,
                                           u16* __restrict__ out) {
  for (int i = blockIdx.x * 256 + threadIdx.x; i < n8; i += gridDim.x * 256) {
    float4 v0 = *((const float4*)x + 2 * (size_t)i);
    float4 v1 = *((const float4*)x + 2 * (size_t)i + 1);
    int4 o;
    o.x = (int)qb16(v0.x, s) | ((int)qb16(v0.y, s) << 16);
    o.y = (int)qb16(v0.z, s) | ((int)qb16(v0.w, s) << 16);
    o.z = (int)qb16(v1.x, s) | ((int)qb16(v1.y, s) << 16);
    o.w = (int)qb16(v1.z, s) | ((int)qb16(v1.w, s) << 16);
    *((int4*)out + i) = o;
  }
}

__global__ __launch_bounds__(256) void quantize_bf16_kernel(const float* __restrict__ x, int n8,
                                                            const unsigned* __restrict__ slot,
                                                            u16* __restrict__ out) {
  quant_body(x, n8, slot_scale(slot), out);
}

__global__ __launch_bounds__(256) void quantize2_kernel(const float* __restrict__ x0,
                                                        const float* __restrict__ x1,
                                                        u16* __restrict__ o0, u16* __restrict__ o1,
                                                        const unsigned* __restrict__ slots, int n8) {
  const int y = blockIdx.y;
  quant_body(y ? x1 : x0, n8, slot_scale(slots + y), y ? o1 : o0);
}

// Quantize weight [K,N] -> transposed bf16 [N][K], 4 weights batched via z
struct W4 { const float* w[4]; u16* wt[4]; };
__global__ __launch_bounds__(256) void quantW4_kernel(W4 a, const unsigned* __restrict__ slots) {
  __shared__ u16 t[64][72];
  const int z = blockIdx.z;
  const float* w = a.w[z];
  u16* wt = a.wt[z];
  const float s = slot_scale(slots + 2 + z);
  const int k0 = blockIdx.y * 64, n0 = blockIdx.x * 64;
  const int tid = threadIdx.x;
#pragma unroll
  for (int rr = 0; rr < 4; rr++) {
    const int row = (tid >> 4) + rr * 16;  // k
    const int col = (tid & 15) * 4;        // n
    float4 v = *(const float4*)&w[(size_t)(k0 + row) * DM_ + n0 + col];
    t[col + 0][row] = qb16(v.x, s);
    t[col + 1][row] = qb16(v.y, s);
    t[col + 2][row] = qb16(v.z, s);
    t[col + 3][row] = qb16(v.w, s);
  }
  __syncthreads();
  const int nr = tid >> 2, kc = (tid & 3) * 16;
  *(int4*)&wt[(size_t)(n0 + nr) * DM_ + k0 + kc] = *(const int4*)&t[nr][kc];
  *(int4*)&wt[(size_t)(n0 + nr) * DM_ + k0 + kc + 8] = *(const int4*)&t[nr][kc + 8];
}

// C[M,N] = exact-int (A[M,K] . Bt[N,K]^T) * (sA*sB) + bias[N].  M=4096, N=K=1024.
// BM=128, BN=64, BK=64. 4 waves 2x2; wave tile 64x32. Double-buffered global_load_lds
// with source-side XOR swizzle (16B chunk ^ (row&7)) -> conflict-even ds_read_b128.
__global__ __launch_bounds__(256) void gemm128_kernel(
    const u16* __restrict__ A, const u16* __restrict__ Bt,
    const unsigned* __restrict__ slotA, const unsigned* __restrict__ slotB,
    const float* __restrict__ bias, float* __restrict__ C,
    unsigned* __restrict__ amax_out) {
  __shared__ u16 As[2][128][64];
  __shared__ u16 Bs[2][64][64];
  const int M = B_ * S_, N = DM_, K = DM_;
  const int id = blockIdx.x;                       // 0..511
  const int lin = (id & 7) * 64 + (id >> 3);       // XCD-contiguous m-panels
  const int by = lin >> 4, bx = lin & 15;
  const int m0 = by * 128, n0 = bx * 64;
  const int tid = threadIdx.x, w = tid >> 6, lane = tid & 63;
  const int c = lane & 15, g = lane >> 4;
  const int wr = w >> 1, wc = w & 1;
  const int lr = lane >> 3, lc = lane & 7;         // staging: 8 lanes/row
  const int schunk = (lc ^ lr) << 3;               // swizzled source chunk (u16 offset)

  f32x4 acc[4][2] = {};

  auto stage = [&](int buf, int kc) {
#pragma unroll
    for (int p = 0; p < 4; ++p) {
      const int r0 = w * 32 + p * 8;
      gload16(&A[(size_t)(m0 + r0 + lr) * K + kc + schunk], &As[buf][r0][0]);
    }
#pragma unroll
    for (int p = 0; p < 2; ++p) {
      const int r0 = w * 16 + p * 8;
      gload16(&Bt[(size_t)(n0 + r0 + lr) * K + kc + schunk], &Bs[buf][r0][0]);
    }
  };

  stage(0, 0);
  __syncthreads();
  for (int kt = 0; kt < 16; ++kt) {
    const int buf = kt & 1;
    if (kt < 15) stage(buf ^ 1, (kt + 1) * 64);
#pragma unroll
    for (int ks = 0; ks < 2; ++ks) {
      const int rswz = ((ks * 4 + g) ^ (c & 7)) << 3;
      bf16x8 b0 = *(const bf16x8*)&Bs[buf][wc * 32 + c][rswz];
      bf16x8 b1 = *(const bf16x8*)&Bs[buf][wc * 32 + 16 + c][rswz];
#pragma unroll
      for (int i = 0; i < 4; ++i) {
        bf16x8 av = *(const bf16x8*)&As[buf][wr * 64 + i * 16 + c][rswz];
        acc[i][0] = MFMA_BF16(av, b0, acc[i][0], 0, 0, 0);
        acc[i][1] = MFMA_BF16(av, b1, acc[i][1], 0, 0, 0);
      }
    }
    __syncthreads();
  }

  const float sAB = slot_scale(slotA) * slot_scale(slotB);
  float am = 0.f;
#pragma unroll
  for (int i = 0; i < 4; ++i)
#pragma unroll
    for (int j = 0; j < 2; ++j)
#pragma unroll
      for (int reg = 0; reg < 4; ++reg) {
        const int m = m0 + wr * 64 + i * 16 + 4 * g + reg;
        const int nn = n0 + wc * 32 + j * 16 + c;
        const float val = __fadd_rn(__fmul_rn(acc[i][j][reg], sAB), bias[nn]);
        C[(size_t)m * N + nn] = val;
        am = fmaxf(am, fabsf(val));
      }
  if (amax_out) {
#pragma unroll
    for (int off = 32; off; off >>= 1) am = fmaxf(am, __shfl_xor(am, off));
    if (lane == 0) atomicMax(amax_out, __float_as_uint(am));
  }
}

// Fused attention: block = (qt, h, b) decoded XCD-grouped; 4 waves x 16 q-rows.
// Two exact passes (pass1: max of pre-div scores, monotone-exact); P kept f32 in LDS,
// 3-way bf16 split on read feeding PV MFMA.
__global__ __launch_bounds__(256) void attn_kernel(
    const u16* __restrict__ qb_, const u16* __restrict__ kb_, const u16* __restrict__ vb_,
    const unsigned* __restrict__ slots, const float* __restrict__ rel,
    float* __restrict__ ao, unsigned* __restrict__ amax_out) {
  __shared__ u16 kbf[64][72];
  __shared__ u16 vT[64][72];        // V^T [d][kv], 16B chunks XORed by (d&3)<<3
  __shared__ float Pf[4][16][68];   // per-wave P rows [q][kv]
  __shared__ float biasT[68];

  const int id = blockIdx.x;        // XCD-grouped decode: co-XCD blocks share (b,h)
  const int rX = id & 7, jX = id >> 3;
  const int qt = jX & 15, gbh = (jX >> 4) * 8 + rX;
  const int h = gbh & 15, b = gbh >> 4;

  const int tid = threadIdx.x;
  const int w = tid >> 6, lane = tid & 63;
  const int c = lane & 15, g = lane >> 4;
  const float sqk = slot_scale(slots + 6) * slot_scale(slots + 7);
  const float sv = slot_scale(slots + 8);
  if (tid < 65) biasT[tid] = rel[tid * D_ + h];

  const int qbase = qt * 64 + w * 16;
  const size_t qrow = ((size_t)(b * S_) + qbase + c) * DM_ + h * 64;
  const bf16x8 qA0 = *(const bf16x8*)&qb_[qrow + g * 8];
  const bf16x8 qA1 = *(const bf16x8*)&qb_[qrow + 32 + g * 8];

  const int sr = tid >> 2, sseg = (tid & 3) * 16;   // K staging
  const int kvp = tid & 31, dq8 = (tid >> 5) * 8;   // V staging
  const size_t kvbase = (size_t)(b * S_) * DM_ + h * 64;

  __syncthreads();
  const float b_lo = biasT[0], b_hi = biasT[64];

  // ---- pass 1: exact row max of pre-div scores ----
  float m2[4] = {-3.4e38f, -3.4e38f, -3.4e38f, -3.4e38f};
  int4 ka = *(const int4*)&kb_[kvbase + (size_t)sr * DM_ + sseg];
  int4 kb2 = *(const int4*)&kb_[kvbase + (size_t)sr * DM_ + sseg + 8];
  for (int ch = 0; ch < 16; ++ch) {
    __syncthreads();
    *(int4*)&kbf[sr][sseg] = ka;
    *(int4*)&kbf[sr][sseg + 8] = kb2;
    if (ch < 15) {
      ka = *(const int4*)&kb_[kvbase + (size_t)((ch + 1) * 64 + sr) * DM_ + sseg];
      kb2 = *(const int4*)&kb_[kvbase + (size_t)((ch + 1) * 64 + sr) * DM_ + sseg + 8];
    }
    __syncthreads();
#pragma unroll
    for (int t = 0; t < 4; ++t) {
      f32x4 sacc = {0.f, 0.f, 0.f, 0.f};
      bf16x8 k0 = *(const bf16x8*)&kbf[t * 16 + c][g * 8];
      bf16x8 k1 = *(const bf16x8*)&kbf[t * 16 + c][32 + g * 8];
      sacc = MFMA_BF16(qA0, k0, sacc, 0, 0, 0);
      sacc = MFMA_BF16(qA1, k1, sacc, 0, 0, 0);
      const int kv0 = ch * 64 + t * 16;
      float bb[4];
      if (kv0 >= qbase + 47) {
        bb[0] = bb[1] = bb[2] = bb[3] = b_lo;
      } else if (qbase >= kv0 + 47) {
        bb[0] = bb[1] = bb[2] = bb[3] = b_hi;
      } else {
        const int jg = kv0 + c;
#pragma unroll
        for (int reg = 0; reg < 4; ++reg) {
          int dp = qbase + 4 * g + reg - jg + 32;
          dp = dp < 0 ? 0 : (dp > 64 ? 64 : dp);
          bb[reg] = biasT[dp];
        }
      }
#pragma unroll
      for (int reg = 0; reg < 4; ++reg)
        m2[reg] = fmaxf(m2[reg], __fadd_rn(__fmul_rn(sacc[reg], sqk), bb[reg]));
    }
  }
#pragma unroll
  for (int off = 1; off <= 8; off <<= 1)
#pragma unroll
    for (int reg = 0; reg < 4; ++reg) m2[reg] = fmaxf(m2[reg], __shfl_xor(m2[reg], off));
  float M[4];
#pragma unroll
  for (int reg = 0; reg < 4; ++reg) M[reg] = div_sf(m2[reg]);  // monotone => exact row max

  // ---- pass 2 ----
  f32x4 oacc[4] = {};
  float ls[4] = {0.f, 0.f, 0.f, 0.f};
  ka = *(const int4*)&kb_[kvbase + (size_t)sr * DM_ + sseg];
  kb2 = *(const int4*)&kb_[kvbase + (size_t)sr * DM_ + sseg + 8];
  int4 va = *(const int4*)&vb_[kvbase + (size_t)(2 * kvp) * DM_ + dq8];
  int4 vb = *(const int4*)&vb_[kvbase + (size_t)(2 * kvp + 1) * DM_ + dq8];
  for (int ch = 0; ch < 16; ++ch) {
    __syncthreads();
    *(int4*)&kbf[sr][sseg] = ka;
    *(int4*)&kbf[sr][sseg + 8] = kb2;
    {
      const u16* pa = (const u16*)&va;
      const u16* pb = (const u16*)&vb;
#pragma unroll
      for (int i = 0; i < 8; ++i) {
        const int col = (2 * kvp) ^ ((i & 3) << 3);
        *(unsigned*)&vT[dq8 + i][col] = (unsigned)pa[i] | ((unsigned)pb[i] << 16);
      }
    }
    if (ch < 15) {
      const size_t nb = kvbase + (size_t)((ch + 1) * 64) * DM_;
      ka = *(const int4*)&kb_[nb + (size_t)sr * DM_ + sseg];
      kb2 = *(const int4*)&kb_[nb + (size_t)sr * DM_ + sseg + 8];
      va = *(const int4*)&vb_[nb + (size_t)(2 * kvp) * DM_ + dq8];
      vb = *(const int4*)&vb_[nb + (size_t)(2 * kvp + 1) * DM_ + dq8];
    }
    __syncthreads();
#pragma unroll
    for (int t = 0; t < 4; ++t) {
      f32x4 sacc = {0.f, 0.f, 0.f, 0.f};
      bf16x8 k0 = *(const bf16x8*)&kbf[t * 16 + c][g * 8];
      bf16x8 k1 = *(const bf16x8*)&kbf[t * 16 + c][32 + g * 8];
      sacc = MFMA_BF16(qA0, k0, sacc, 0, 0, 0);
      sacc = MFMA_BF16(qA1, k1, sacc, 0, 0, 0);
      const int kv0 = ch * 64 + t * 16;
      float bb[4];
      if (kv0 >= qbase + 47) {
        bb[0] = bb[1] = bb[2] = bb[3] = b_lo;
      } else if (qbase >= kv0 + 47) {
        bb[0] = bb[1] = bb[2] = bb[3] = b_hi;
      } else {
        const int jg = kv0 + c;
#pragma unroll
        for (int reg = 0; reg < 4; ++reg) {
          int dp = qbase + 4 * g + reg - jg + 32;
          dp = dp < 0 ? 0 : (dp > 64 ? 64 : dp);
          bb[reg] = biasT[dp];
        }
      }
      float* pw = &Pf[w][4 * g][t * 16 + c];
#pragma unroll
      for (int reg = 0; reg < 4; ++reg) {
        const float sc = div_sf(__fadd_rn(__fmul_rn(sacc[reg], sqk), bb[reg]));
        const float e = expf(sc - M[reg]);
        ls[reg] += e;
        pw[reg * 68] = e;
      }
    }
    // PV: read own wave's P rows, split 3-way bf16, MFMA against vT
#pragma unroll
    for (int ks = 0; ks < 2; ++ks) {
      const float* pr = &Pf[w][c][ks * 32 + g * 8];
      float4 e0 = *(const float4*)pr;
      float4 e1 = *(const float4*)(pr + 4);
      float ev[8] = {e0.x, e0.y, e0.z, e0.w, e1.x, e1.y, e1.z, e1.w};
      bf16x8 ph, pm, pl;
#pragma unroll
      for (int jj = 0; jj < 8; ++jj) {
        const float e = ev[jj];
        const u16 hu = f2b(e);
        const float r1 = __fsub_rn(e, b2f(hu));
        const u16 mu = f2b(r1);
        const float r2 = __fsub_rn(r1, b2f(mu));
        const u16 lu = f2b(r2);
        ph[jj] = (short)hu;
        pm[jj] = (short)mu;
        pl[jj] = (short)lu;
      }
#pragma unroll
      for (int n = 0; n < 4; ++n) {
        const int dd = 16 * n + c;
        const int cc = (ks * 32 + 8 * g) ^ ((dd & 3) << 3);
        bf16x8 vv = *(const bf16x8*)&vT[dd][cc];
        oacc[n] = MFMA_BF16(ph, vv, oacc[n], 0, 0, 0);
        oacc[n] = MFMA_BF16(pm, vv, oacc[n], 0, 0, 0);
        oacc[n] = MFMA_BF16(pl, vv, oacc[n], 0, 0, 0);
      }
    }
  }
#pragma unroll
  for (int off = 1; off <= 8; off <<= 1)
#pragma unroll
    for (int reg = 0; reg < 4; ++reg) ls[reg] += __shfl_xor(ls[reg], off);

  float am = 0.f;
#pragma unroll
  for (int reg = 0; reg < 4; ++reg) {
    const float L = ls[reg] + 1e-6f;  // reference: /(sum + 1e-6)
    const size_t orow = ((size_t)(b * S_) + qbase + 4 * g + reg) * DM_ + h * 64;
#pragma unroll
    for (int n = 0; n < 4; ++n) {
      const float val = __fmul_rn(oacc[n][reg] / L, sv);
      ao[orow + n * 16 + c] = val;
      am = fmaxf(am, fabsf(val));
    }
  }
#pragma unroll
  for (int off = 1; off <= 32; off <<= 1) am = fmaxf(am, __shfl_xor(am, off));
  if (lane == 0) atomicMax(amax_out, __float_as_uint(am));
}

extern "C" void kernel_launch(void* const* d_in, const int* in_sizes, int n_in,
                              void* d_out, int out_size, void* d_ws, size_t ws_size,
                              hipStream_t stream) {
  const float* inputs_q  = (const float*)d_in[0];
  const float* inputs_kv = (const float*)d_in[1];
  const float* Wq = (const float*)d_in[2];
  const float* bq = (const float*)d_in[3];
  const float* Wk = (const float*)d_in[4];
  const float* bk = (const float*)d_in[5];
  const float* Wv = (const float*)d_in[6];
  const float* bv = (const float*)d_in[7];
  const float* Wo = (const float*)d_in[8];
  const float* bo = (const float*)d_in[9];
  const float* rel = (const float*)d_in[10];
  float* out = (float*)d_out;

  char* ws = (char*)d_ws;
  constexpr size_t MB = 1024 * 1024;
  // slots: 0 sx_q, 1 sx_kv, 2 sWq, 3 sWk, 4 sWv, 5 sWo, 6 sq, 7 sk, 8 sv, 9 sao
  unsigned* slots = (unsigned*)ws;
  u16* xq_b  = (u16*)(ws + 1024);
  u16* xkv_b = (u16*)((char*)xq_b + 8 * MB);
  u16* wq_b  = (u16*)((char*)xkv_b + 8 * MB);
  u16* wk_b  = (u16*)((char*)wq_b + 2 * MB);
  u16* wv_b  = (u16*)((char*)wk_b + 2 * MB);
  u16* wo_b  = (u16*)((char*)wv_b + 2 * MB);
  u16* q_b   = (u16*)((char*)wo_b + 2 * MB);
  u16* k_b   = (u16*)((char*)q_b + 8 * MB);
  u16* v_b   = (u16*)((char*)k_b + 8 * MB);
  u16* ao_b  = (u16*)((char*)v_b + 8 * MB);
  float* tf  = (float*)((char*)ao_b + 8 * MB);  // 16 MB f32 scratch
  (void)ws_size; (void)in_sizes; (void)n_in; (void)out_size;

  const int n4_x = (B_ * S_ * DM_) / 4, n4_w = (DM_ * DM_) / 4;
  const int n8_x = (B_ * S_ * DM_) / 8;

  zero_slots_kernel<<<1, 64, 0, stream>>>(slots);

  Ptr6 a6;
  a6.p[0] = inputs_q;  a6.n4[0] = n4_x;
  a6.p[1] = inputs_kv; a6.n4[1] = n4_x;
  a6.p[2] = Wq; a6.n4[2] = n4_w;
  a6.p[3] = Wk; a6.n4[3] = n4_w;
  a6.p[4] = Wv; a6.n4[4] = n4_w;
  a6.p[5] = Wo; a6.n4[5] = n4_w;
  absmax6_kernel<<<dim3(128, 6), 256, 0, stream>>>(a6, slots);

  quantize2_kernel<<<dim3(512, 2), 256, 0, stream>>>(inputs_q, inputs_kv, xq_b, xkv_b,
                                                     slots, n8_x);
  W4 w4;
  w4.w[0] = Wq; w4.wt[0] = wq_b;
  w4.w[1] = Wk; w4.wt[1] = wk_b;
  w4.w[2] = Wv; w4.wt[2] = wv_b;
  w4.w[3] = Wo; w4.wt[3] = wo_b;
  quantW4_kernel<<<dim3(16, 16, 4), 256, 0, stream>>>(w4, slots);

  gemm128_kernel<<<512, 256, 0, stream>>>(xq_b, wq_b, slots + 0, slots + 2, bq, tf, slots + 6);
  quantize_bf16_kernel<<<1024, 256, 0, stream>>>(tf, n8_x, slots + 6, q_b);
  gemm128_kernel<<<512, 256, 0, stream>>>(xkv_b, wk_b, slots + 1, slots + 3, bk, tf, slots + 7);
  quantize_bf16_kernel<<<1024, 256, 0, stream>>>(tf, n8_x, slots + 7, k_b);
  gemm128_kernel<<<512, 256, 0, stream>>>(xkv_b, wv_b, slots + 1, slots + 4, bv, tf, slots + 8);
  quantize_bf16_kernel<<<1024, 256, 0, stream>>>(tf, n8_x, slots + 8, v_b);

  attn_kernel<<<1024, 256, 0, stream>>>(q_b, k_b, v_b, slots, rel, tf, slots + 9);

  quantize_bf16_kernel<<<1024, 256, 0, stream>>>(tf, n8_x, slots + 9, ao_b);

  gemm128_kernel<<<512, 256, 0, stream>>>(ao_b, wo_b, slots + 9, slots + 5, bo, out, nullptr);
}